// Round 2
// baseline (766.175 us; speedup 1.0000x reference)
//
#include <hip/hip_runtime.h>
#include <cstdint>
#include <cstddef>

// Problem constants
#define BB 32
#define SS 2048
#define DD 1024
#define MM (BB * SS)   // 65536 rows of the big GEMM

typedef __bf16 bf16_t;
typedef __bf16 bf16x4 __attribute__((ext_vector_type(4)));
typedef __bf16 bf16x8 __attribute__((ext_vector_type(8)));
typedef float  f32x4  __attribute__((ext_vector_type(4)));

typedef __attribute__((address_space(1))) unsigned int gu32;
typedef __attribute__((address_space(3))) unsigned int lu32;

__device__ __forceinline__ void async_copy16(const void* g, void* l) {
  __builtin_amdgcn_global_load_lds((gu32*)g, (lu32*)l, 16, 0, 0);
}

// ---------------------------------------------------------------------------
// Kernel 1: W1_enc (fp32, [k][n]) -> W1T (bf16, [n][k])  (transpose + convert)
// ---------------------------------------------------------------------------
__global__ __launch_bounds__(256) void conv_w1t_kernel(
    const float* __restrict__ W1, bf16_t* __restrict__ W1T) {
  __shared__ float tile[64][65];
  const int bk = (blockIdx.x & 15) * 64;   // k tile origin
  const int bn = (blockIdx.x >> 4) * 64;   // n tile origin
  const int tx = threadIdx.x & 63;
  const int ty = threadIdx.x >> 6;         // 0..3
#pragma unroll
  for (int i = 0; i < 16; ++i) {
    const int kr = i * 4 + ty;
    tile[kr][tx] = W1[(size_t)(bk + kr) * 1024 + bn + tx];
  }
  __syncthreads();
#pragma unroll
  for (int i = 0; i < 16; ++i) {
    const int nr = i * 4 + ty;
    W1T[(size_t)(bn + nr) * 1024 + bk + tx] = (bf16_t)tile[tx][nr];
  }
}

// ---------------------------------------------------------------------------
// Kernel 2: dec_proj[b][u] = h_dec[b,:] @ W1_dec[:,u] + b1[u]  (fp32)
// Split-K over 2 halves; grid 256 = (b, u-chunk of 128). Also zeroes e2.
// ---------------------------------------------------------------------------
__global__ __launch_bounds__(256) void dec_proj_kernel(
    const float* __restrict__ hDec, const float* __restrict__ W1,
    const float* __restrict__ b1, float* __restrict__ dp,
    float* __restrict__ e2) {
  __shared__ float sred[256];
  const int bidx = blockIdx.x;
  const int b  = bidx >> 3;
  const int uc = bidx & 7;
  const int t  = threadIdx.x;
  e2[bidx * 256 + t] = 0.f;  // 256*256 == 65536
  const int u  = uc * 128 + (t & 127);
  const int kh = t >> 7;
  const float* wd = W1 + (size_t)1024 * 1024 + u;   // W1_dec = rows 1024..2047
  const float* hd = hDec + b * 1024 + kh * 512;
  float acc = 0.f;
#pragma unroll 4
  for (int k = 0; k < 512; ++k)
    acc += hd[k] * wd[(size_t)(kh * 512 + k) * 1024];
  sred[t] = acc;
  __syncthreads();
  if (t < 128) dp[b * 1024 + u] = sred[t] + sred[t + 128] + b1[u];
}

// ---------------------------------------------------------------------------
// Kernel 3: fused bf16 MFMA GEMM + tanh + W2 row-reduction -> e2 partials
//   e2[m] += sum_n tanh(hEnc[m,:]@W1enc[:,n] + dp[b,n]) * W2[n]
// m97-shape: 128x128 tile, 4 waves in 2x2, each 64x64 (4x4 frags 16x16x32).
// grid = 4096 = 512 m-tiles x 8 n-blocks, XCD-swizzled so the 8 n-blocks of
// one m-tile land on the same XCD (A-slab read once from HBM).
// LDS: sA 8KB + sB 8KB, 64B rows, 16B-chunk XOR swizzle (0 bank conflicts).
// ---------------------------------------------------------------------------
__global__ __launch_bounds__(256, 3) void fused_gemm_kernel(
    const float* __restrict__ hEnc, const bf16_t* __restrict__ W1T,
    const float* __restrict__ dp, const float* __restrict__ W2,
    float* __restrict__ e2) {
  __shared__ bf16_t sA[128 * 32];
  __shared__ bf16_t sB[128 * 32];

  const int tid  = threadIdx.x;
  const int lane = tid & 63;
  const int wv   = tid >> 6;
  const int wm   = wv >> 1;
  const int wn   = wv & 1;

  const int bid   = blockIdx.x;
  const int mtile = ((bid >> 6) << 3) | (bid & 7);  // [0,512): same-XCD groups share m-tile
  const int nblk  = (bid >> 3) & 7;                 // [0,8)
  const int m0    = mtile * 128;
  const int n0    = nblk * 128;
  const int b     = m0 >> 11;                       // 2048 rows per batch elem

  const int col = lane & 15;
  const int q   = lane >> 4;
  const int sw  = q ^ ((col >> 1) & 3);             // XOR 16B-chunk swizzle

  f32x4 acc[4][4];
#pragma unroll
  for (int mi = 0; mi < 4; ++mi)
#pragma unroll
    for (int ni = 0; ni < 4; ++ni)
      acc[mi][ni] = (f32x4){0.f, 0.f, 0.f, 0.f};

  char* sAc = (char*)sA;
  char* sBc = (char*)sB;

  // A staging: thread -> (row = tid&127, k-half = tid>>7): 16 fp32 -> 16 bf16
  const int arow = tid & 127;
  const int ah   = tid >> 7;
  const int asel = (arow >> 1) & 3;
  const float* aG = hEnc + (size_t)(m0 + arow) * 1024 + ah * 16;
  const unsigned aw0 = arow * 64u + (unsigned)(((2 * ah)     ^ asel) << 4);
  const unsigned aw1 = arow * 64u + (unsigned)(((2 * ah + 1) ^ asel) << 4);

  // B staging: wave wv fills slabs s0,s1 (16 rows each) via global_load_lds
  const int lrow = lane >> 2;                        // row within slab
  const int lc   = (lane & 3) ^ ((lane >> 3) & 3);   // logical k-chunk (swizzle)
  const int s0   = wv * 2, s1 = wv * 2 + 1;
  const bf16_t* bG0 = W1T + (size_t)(n0 + s0 * 16 + lrow) * 1024 + lc * 8;
  const bf16_t* bG1 = W1T + (size_t)(n0 + s1 * 16 + lrow) * 1024 + lc * 8;

  const unsigned a_rd = (unsigned)((wm * 64 + col) * 64 + sw * 16);
  const unsigned b_rd = (unsigned)((wn * 64 + col) * 64 + sw * 16);

#pragma unroll 1
  for (int k0 = 0; k0 < 1024; k0 += 32) {
    // B: async global->LDS (16B/lane, wave-uniform base)
    async_copy16(bG0 + k0, sBc + s0 * 1024);
    async_copy16(bG1 + k0, sBc + s1 * 1024);
    // A: fp32 load, convert, LDS write (two swizzled 16B chunks)
    {
      const float4 v0 = *(const float4*)(aG + k0);
      const float4 v1 = *(const float4*)(aG + k0 + 4);
      const float4 v2 = *(const float4*)(aG + k0 + 8);
      const float4 v3 = *(const float4*)(aG + k0 + 12);
      bf16x8 lo, hi;
      lo[0] = (bf16_t)v0.x; lo[1] = (bf16_t)v0.y; lo[2] = (bf16_t)v0.z; lo[3] = (bf16_t)v0.w;
      lo[4] = (bf16_t)v1.x; lo[5] = (bf16_t)v1.y; lo[6] = (bf16_t)v1.z; lo[7] = (bf16_t)v1.w;
      hi[0] = (bf16_t)v2.x; hi[1] = (bf16_t)v2.y; hi[2] = (bf16_t)v2.z; hi[3] = (bf16_t)v2.w;
      hi[4] = (bf16_t)v3.x; hi[5] = (bf16_t)v3.y; hi[6] = (bf16_t)v3.z; hi[7] = (bf16_t)v3.w;
      *(bf16x8*)(sAc + aw0) = lo;
      *(bf16x8*)(sAc + aw1) = hi;
    }
    __syncthreads();
    bf16x8 af[4], bf[4];
#pragma unroll
    for (int mi = 0; mi < 4; ++mi) af[mi] = *(const bf16x8*)(sAc + a_rd + mi * 1024);
#pragma unroll
    for (int ni = 0; ni < 4; ++ni) bf[ni] = *(const bf16x8*)(sBc + b_rd + ni * 1024);
#pragma unroll
    for (int mi = 0; mi < 4; ++mi)
#pragma unroll
      for (int ni = 0; ni < 4; ++ni)
        acc[mi][ni] = __builtin_amdgcn_mfma_f32_16x16x32_bf16(af[mi], bf[ni], acc[mi][ni], 0, 0, 0);
    __syncthreads();
  }

  // Epilogue: rs[mi][r] = sum_n tanh(acc + dp[n]) * W2[n], reduce 16 cols,
  // atomicAdd partials (8 n-blocks x 2 wn-waves accumulate per e2[m]).
  float rs[4][4];
#pragma unroll
  for (int mi = 0; mi < 4; ++mi)
#pragma unroll
    for (int r = 0; r < 4; ++r) rs[mi][r] = 0.f;

  const float* dpb = dp + b * 1024 + n0 + wn * 64 + col;
  const float* w2b = W2 + n0 + wn * 64 + col;
#pragma unroll
  for (int ni = 0; ni < 4; ++ni) {
    const float dpn = dpb[ni * 16];
    const float w2n = w2b[ni * 16];
#pragma unroll
    for (int mi = 0; mi < 4; ++mi)
#pragma unroll
      for (int r = 0; r < 4; ++r) {
        const float x = acc[mi][ni][r] + dpn;
        const float e = __expf(2.f * x);       // tanh(x) = 1 - 2/(e^{2x}+1)
        const float th = 1.f - 2.f / (e + 1.f);
        rs[mi][r] += th * w2n;
      }
  }
#pragma unroll
  for (int off = 1; off < 16; off <<= 1)
#pragma unroll
    for (int mi = 0; mi < 4; ++mi)
#pragma unroll
      for (int r = 0; r < 4; ++r)
        rs[mi][r] += __shfl_xor(rs[mi][r], off, 64);
  if (col == 0) {
#pragma unroll
    for (int mi = 0; mi < 4; ++mi)
#pragma unroll
      for (int r = 0; r < 4; ++r)
        atomicAdd(&e2[m0 + wm * 64 + mi * 16 + q * 4 + r], rs[mi][r]);
  }
}

// ---------------------------------------------------------------------------
// Kernel 4: per-b softmax over S of relu(e2 + b2); writes attn weights,
// zeroes context region (kernel 5 accumulates with atomics).
// ---------------------------------------------------------------------------
__global__ __launch_bounds__(256) void softmax_kernel(
    const float* __restrict__ e2, const float* __restrict__ b2,
    float* __restrict__ attn, float* __restrict__ ctx) {
  const int b = blockIdx.x;
  const int t = threadIdx.x;
  __shared__ float sred[4];
  const float b2v = b2[0];
  float v[8];
  float lmax = 0.f;  // relu output >= 0
#pragma unroll
  for (int i = 0; i < 8; ++i) {
    v[i] = fmaxf(e2[b * 2048 + i * 256 + t] + b2v, 0.f);  // energies2
    lmax = fmaxf(lmax, v[i]);
  }
#pragma unroll
  for (int off = 1; off < 64; off <<= 1) lmax = fmaxf(lmax, __shfl_xor(lmax, off, 64));
  const int wv = t >> 6;
  const int lane = t & 63;
  if (lane == 0) sred[wv] = lmax;
  __syncthreads();
  const float bmax = fmaxf(fmaxf(sred[0], sred[1]), fmaxf(sred[2], sred[3]));
  __syncthreads();
  float ev[8];
  float lsum = 0.f;
#pragma unroll
  for (int i = 0; i < 8; ++i) { ev[i] = __expf(v[i] - bmax); lsum += ev[i]; }
#pragma unroll
  for (int off = 1; off < 64; off <<= 1) lsum += __shfl_xor(lsum, off, 64);
  if (lane == 0) sred[wv] = lsum;
  __syncthreads();
  const float inv = 1.f / (sred[0] + sred[1] + sred[2] + sred[3]);
#pragma unroll
  for (int i = 0; i < 8; ++i) attn[b * 2048 + i * 256 + t] = ev[i] * inv;
#pragma unroll
  for (int i = 0; i < 4; ++i) ctx[b * 1024 + i * 256 + t] = 0.f;
}

// ---------------------------------------------------------------------------
// Kernel 5: context[b,d] = sum_s attn[b,s] * hEnc[b,s,d]
// grid = 32 b x 32 s-chunks(64), 256 threads x float4 covers d=1024.
// ---------------------------------------------------------------------------
__global__ __launch_bounds__(256) void context_kernel(
    const float* __restrict__ hEnc, const float* __restrict__ attn,
    float* __restrict__ ctx) {
  const int b = blockIdx.x >> 5;
  const int c = blockIdx.x & 31;
  const int t = threadIdx.x;
  __shared__ float w[64];
  if (t < 64) w[t] = attn[b * 2048 + c * 64 + t];
  __syncthreads();
  float ax = 0.f, ay = 0.f, az = 0.f, aw = 0.f;
  const float* base = hEnc + ((size_t)b * 2048 + c * 64) * 1024 + t * 4;
#pragma unroll 4
  for (int s = 0; s < 64; ++s) {
    const float4 h4 = *(const float4*)(base + (size_t)s * 1024);
    const float ws = w[s];
    ax += ws * h4.x; ay += ws * h4.y; az += ws * h4.z; aw += ws * h4.w;
  }
  float* o = ctx + b * 1024 + t * 4;
  atomicAdd(o + 0, ax);
  atomicAdd(o + 1, ay);
  atomicAdd(o + 2, az);
  atomicAdd(o + 3, aw);
}

// ---------------------------------------------------------------------------
extern "C" void kernel_launch(void* const* d_in, const int* in_sizes, int n_in,
                              void* d_out, int out_size, void* d_ws, size_t ws_size,
                              hipStream_t stream) {
  const float* hEnc = (const float*)d_in[0];  // (32,2048,1024) fp32
  const float* hDec = (const float*)d_in[1];  // (32,1024) fp32
  const float* W1   = (const float*)d_in[2];  // (2048,1024) fp32
  const float* b1   = (const float*)d_in[3];  // (1024,) fp32
  const float* W2   = (const float*)d_in[4];  // (1024,1) fp32
  const float* b2   = (const float*)d_in[5];  // (1,) fp32
  float* out = (float*)d_out;                 // [0,32768): context; [32768,98304): attn

  // workspace: W1T bf16 2MB | dp fp32 128KB | e2 fp32 256KB
  char* ws = (char*)d_ws;
  bf16_t* W1T = (bf16_t*)ws;
  float*  dp  = (float*)(ws + 2u * 1024 * 1024);
  float*  e2  = (float*)(ws + 2u * 1024 * 1024 + 128u * 1024);

  conv_w1t_kernel<<<256, 256, 0, stream>>>(W1, W1T);
  dec_proj_kernel<<<256, 256, 0, stream>>>(hDec, W1, b1, dp, e2);
  fused_gemm_kernel<<<4096, 256, 0, stream>>>(hEnc, W1T, dp, W2, e2);
  softmax_kernel<<<32, 256, 0, stream>>>(e2, b2, out + 32768, out);
  context_kernel<<<1024, 256, 0, stream>>>(hEnc, out + 32768, out);
}

// Round 3
// 689.636 us; speedup vs baseline: 1.1110x; 1.1110x over previous
//
#include <hip/hip_runtime.h>
#include <cstdint>
#include <cstddef>

// Problem constants
#define BB 32
#define SS 2048
#define DD 1024
#define MM (BB * SS)   // 65536 rows of the big GEMM

typedef __bf16 bf16_t;
typedef __bf16 bf16x4 __attribute__((ext_vector_type(4)));
typedef __bf16 bf16x8 __attribute__((ext_vector_type(8)));
typedef float  f32x4  __attribute__((ext_vector_type(4)));

typedef __attribute__((address_space(1))) unsigned int gu32;
typedef __attribute__((address_space(3))) unsigned int lu32;

__device__ __forceinline__ void async_copy16(const void* g, void* l) {
  __builtin_amdgcn_global_load_lds((gu32*)g, (lu32*)l, 16, 0, 0);
}

// ---------------------------------------------------------------------------
// Kernel 0: hEnc fp32 -> bf16 (streaming convert). 4096 blocks x 256 thr,
// 16 float4 per thread, stride 1M threads -> fully coalesced.
// ---------------------------------------------------------------------------
__global__ __launch_bounds__(256) void conv_henc_kernel(
    const float* __restrict__ src, bf16_t* __restrict__ dst) {
  const size_t g = (size_t)blockIdx.x * 256 + threadIdx.x;
  const float4* s4 = (const float4*)src;
#pragma unroll
  for (int j = 0; j < 16; ++j) {
    const size_t idx = g + (size_t)j * (4096u * 256u);
    const float4 v = s4[idx];
    bf16x4 o;
    o[0] = (bf16_t)v.x; o[1] = (bf16_t)v.y; o[2] = (bf16_t)v.z; o[3] = (bf16_t)v.w;
    *(bf16x4*)(dst + idx * 4) = o;
  }
}

// ---------------------------------------------------------------------------
// Kernel 1: W1_enc (fp32, [k][n]) -> W1T (bf16, [n][k])  (transpose + convert)
// ---------------------------------------------------------------------------
__global__ __launch_bounds__(256) void conv_w1t_kernel(
    const float* __restrict__ W1, bf16_t* __restrict__ W1T) {
  __shared__ float tile[64][65];
  const int bk = (blockIdx.x & 15) * 64;   // k tile origin
  const int bn = (blockIdx.x >> 4) * 64;   // n tile origin
  const int tx = threadIdx.x & 63;
  const int ty = threadIdx.x >> 6;         // 0..3
#pragma unroll
  for (int i = 0; i < 16; ++i) {
    const int kr = i * 4 + ty;
    tile[kr][tx] = W1[(size_t)(bk + kr) * 1024 + bn + tx];
  }
  __syncthreads();
#pragma unroll
  for (int i = 0; i < 16; ++i) {
    const int nr = i * 4 + ty;
    W1T[(size_t)(bn + nr) * 1024 + bk + tx] = (bf16_t)tile[tx][nr];
  }
}

// ---------------------------------------------------------------------------
// Kernel 2: dec_proj[b][u] = h_dec[b,:] @ W1_dec[:,u] + b1[u]  (fp32)
// Split-K over 2 halves; grid 256 = (b, u-chunk of 128). Also zeroes e2.
// ---------------------------------------------------------------------------
__global__ __launch_bounds__(256) void dec_proj_kernel(
    const float* __restrict__ hDec, const float* __restrict__ W1,
    const float* __restrict__ b1, float* __restrict__ dp,
    float* __restrict__ e2) {
  __shared__ float sred[256];
  const int bidx = blockIdx.x;
  const int b  = bidx >> 3;
  const int uc = bidx & 7;
  const int t  = threadIdx.x;
  e2[bidx * 256 + t] = 0.f;  // 256*256 == 65536
  const int u  = uc * 128 + (t & 127);
  const int kh = t >> 7;
  const float* wd = W1 + (size_t)1024 * 1024 + u;   // W1_dec = rows 1024..2047
  const float* hd = hDec + b * 1024 + kh * 512;
  float acc = 0.f;
#pragma unroll 4
  for (int k = 0; k < 512; ++k)
    acc += hd[k] * wd[(size_t)(kh * 512 + k) * 1024];
  sred[t] = acc;
  __syncthreads();
  if (t < 128) dp[b * 1024 + u] = sred[t] + sred[t + 128] + b1[u];
}

// ---------------------------------------------------------------------------
// Kernel 3: fused bf16 MFMA GEMM + tanh + W2 row-reduction -> e2 partials
//   e2[m] += sum_n tanh(hEnc[m,:]@W1enc[:,n] + dp[b,n]) * W2[n]
// m97-shape: 128x128 tile, 4 waves 2x2, each 64x64 (4x4 frags of 16x16x32).
// ABF16=true: A staged from bf16 copy via global_load_lds (m97-identical).
// ABF16=false (small-ws fallback): A fp32, 16B/lane coalesced + in-reg cvt.
// grid = 4096 = 512 m-tiles x 8 n-blocks, XCD-swizzled (8 n-blocks of one
// m-tile land on the same XCD -> A slab read from HBM once).
// LDS: sA 8KB + sB 8KB, 64B rows, 16B-chunk XOR swizzle (0 bank conflicts).
// ---------------------------------------------------------------------------
template <bool ABF16>
__global__ __launch_bounds__(256, 4) void fused_gemm_kernel(
    const float* __restrict__ hEnc32, const bf16_t* __restrict__ hEncB,
    const bf16_t* __restrict__ W1T, const float* __restrict__ dp,
    const float* __restrict__ W2, float* __restrict__ e2) {
  __shared__ bf16_t sA[128 * 32];
  __shared__ bf16_t sB[128 * 32];

  const int tid  = threadIdx.x;
  const int lane = tid & 63;
  const int wv   = tid >> 6;
  const int wm   = wv >> 1;
  const int wn   = wv & 1;

  const int bid   = blockIdx.x;
  const int mtile = ((bid >> 6) << 3) | (bid & 7);  // [0,512)
  const int nblk  = (bid >> 3) & 7;                 // [0,8)
  const int m0    = mtile * 128;
  const int n0    = nblk * 128;
  const int b     = m0 >> 11;                       // 2048 rows per batch elem

  const int col = lane & 15;
  const int q   = lane >> 4;
  const int sw  = q ^ ((col >> 1) & 3);             // XOR 16B-chunk swizzle

  f32x4 acc[4][4];
#pragma unroll
  for (int mi = 0; mi < 4; ++mi)
#pragma unroll
    for (int ni = 0; ni < 4; ++ni)
      acc[mi][ni] = (f32x4){0.f, 0.f, 0.f, 0.f};

  char* sAc = (char*)sA;
  char* sBc = (char*)sB;

  // async-staging lane map (A and B): slab row = lane>>2, swizzled k-chunk
  const int lrow = lane >> 2;
  const int lc   = (lane & 3) ^ ((lane >> 3) & 3);
  const int s0   = wv * 2, s1 = wv * 2 + 1;
  const bf16_t* bG0 = W1T + (size_t)(n0 + s0 * 16 + lrow) * 1024 + lc * 8;
  const bf16_t* bG1 = W1T + (size_t)(n0 + s1 * 16 + lrow) * 1024 + lc * 8;
  const bf16_t* aG0 = ABF16 ? hEncB + (size_t)(m0 + s0 * 16 + lrow) * 1024 + lc * 8 : nullptr;
  const bf16_t* aG1 = ABF16 ? hEncB + (size_t)(m0 + s1 * 16 + lrow) * 1024 + lc * 8 : nullptr;

  // fallback fp32-A staging map: 4 sub-iters, (row = i*32 + tid>>3, 16B chunk tid&7)
  const int frow = tid >> 3;
  const int fc   = tid & 7;
  const float*   aG32  = ABF16 ? nullptr : hEnc32 + (size_t)(m0 + frow) * 1024 + fc * 4;
  const unsigned fpch  = (unsigned)((fc >> 1) ^ ((frow >> 1) & 3));
  const unsigned f_off = frow * 64u + fpch * 16u + (unsigned)(fc & 1) * 8u;

  const unsigned a_rd = (unsigned)((wm * 64 + col) * 64 + sw * 16);
  const unsigned b_rd = (unsigned)((wn * 64 + col) * 64 + sw * 16);

#pragma unroll 1
  for (int k0 = 0; k0 < 1024; k0 += 32) {
    async_copy16(bG0 + k0, sBc + s0 * 1024);
    async_copy16(bG1 + k0, sBc + s1 * 1024);
    if constexpr (ABF16) {
      async_copy16(aG0 + k0, sAc + s0 * 1024);
      async_copy16(aG1 + k0, sAc + s1 * 1024);
    } else {
#pragma unroll
      for (int i = 0; i < 4; ++i) {
        const float4 v = *(const float4*)(aG32 + k0 + (size_t)i * 32 * 1024);
        bf16x4 a4;
        a4[0] = (bf16_t)v.x; a4[1] = (bf16_t)v.y;
        a4[2] = (bf16_t)v.z; a4[3] = (bf16_t)v.w;
        *(bf16x4*)(sAc + f_off + i * 2048) = a4;
      }
    }
    __syncthreads();
    bf16x8 af[4], bf[4];
#pragma unroll
    for (int mi = 0; mi < 4; ++mi) af[mi] = *(const bf16x8*)(sAc + a_rd + mi * 1024);
#pragma unroll
    for (int ni = 0; ni < 4; ++ni) bf[ni] = *(const bf16x8*)(sBc + b_rd + ni * 1024);
#pragma unroll
    for (int mi = 0; mi < 4; ++mi)
#pragma unroll
      for (int ni = 0; ni < 4; ++ni)
        acc[mi][ni] = __builtin_amdgcn_mfma_f32_16x16x32_bf16(af[mi], bf[ni], acc[mi][ni], 0, 0, 0);
    __syncthreads();
  }

  // Epilogue: rs = sum_n tanh(acc + dp[n]) * W2[n]; butterfly over 16 cols;
  // atomicAdd partials (8 n-blocks x 2 wn-waves accumulate per e2[m]).
  float rs[4][4];
#pragma unroll
  for (int mi = 0; mi < 4; ++mi)
#pragma unroll
    for (int r = 0; r < 4; ++r) rs[mi][r] = 0.f;

  const float* dpb = dp + b * 1024 + n0 + wn * 64 + col;
  const float* w2b = W2 + n0 + wn * 64 + col;
#pragma unroll
  for (int ni = 0; ni < 4; ++ni) {
    const float dpn = dpb[ni * 16];
    const float w2n = w2b[ni * 16];
#pragma unroll
    for (int mi = 0; mi < 4; ++mi)
#pragma unroll
      for (int r = 0; r < 4; ++r) {
        const float x = acc[mi][ni][r] + dpn;
        const float e = __expf(2.f * x);       // tanh(x) = 1 - 2/(e^{2x}+1)
        const float th = 1.f - 2.f / (e + 1.f);
        rs[mi][r] += th * w2n;
      }
  }
#pragma unroll
  for (int off = 1; off < 16; off <<= 1)
#pragma unroll
    for (int mi = 0; mi < 4; ++mi)
#pragma unroll
      for (int r = 0; r < 4; ++r)
        rs[mi][r] += __shfl_xor(rs[mi][r], off, 64);
  if (col == 0) {
#pragma unroll
    for (int mi = 0; mi < 4; ++mi)
#pragma unroll
      for (int r = 0; r < 4; ++r)
        atomicAdd(&e2[m0 + wm * 64 + mi * 16 + q * 4 + r], rs[mi][r]);
  }
}

// ---------------------------------------------------------------------------
// Kernel 4: per-b softmax over S of relu(e2 + b2); writes attn weights,
// zeroes context region (kernel 5 accumulates with atomics).
// ---------------------------------------------------------------------------
__global__ __launch_bounds__(256) void softmax_kernel(
    const float* __restrict__ e2, const float* __restrict__ b2,
    float* __restrict__ attn, float* __restrict__ ctx) {
  const int b = blockIdx.x;
  const int t = threadIdx.x;
  __shared__ float sred[4];
  const float b2v = b2[0];
  float v[8];
  float lmax = 0.f;  // relu output >= 0
#pragma unroll
  for (int i = 0; i < 8; ++i) {
    v[i] = fmaxf(e2[b * 2048 + i * 256 + t] + b2v, 0.f);  // energies2
    lmax = fmaxf(lmax, v[i]);
  }
#pragma unroll
  for (int off = 1; off < 64; off <<= 1) lmax = fmaxf(lmax, __shfl_xor(lmax, off, 64));
  const int wv = t >> 6;
  const int lane = t & 63;
  if (lane == 0) sred[wv] = lmax;
  __syncthreads();
  const float bmax = fmaxf(fmaxf(sred[0], sred[1]), fmaxf(sred[2], sred[3]));
  __syncthreads();
  float ev[8];
  float lsum = 0.f;
#pragma unroll
  for (int i = 0; i < 8; ++i) { ev[i] = __expf(v[i] - bmax); lsum += ev[i]; }
#pragma unroll
  for (int off = 1; off < 64; off <<= 1) lsum += __shfl_xor(lsum, off, 64);
  if (lane == 0) sred[wv] = lsum;
  __syncthreads();
  const float inv = 1.f / (sred[0] + sred[1] + sred[2] + sred[3]);
#pragma unroll
  for (int i = 0; i < 8; ++i) attn[b * 2048 + i * 256 + t] = ev[i] * inv;
#pragma unroll
  for (int i = 0; i < 4; ++i) ctx[b * 1024 + i * 256 + t] = 0.f;
}

// ---------------------------------------------------------------------------
// Kernel 5: context[b,d] = sum_s attn[b,s] * hEnc[b,s,d]
// bf16 variant (reads the converted copy: half the HBM traffic).
// ---------------------------------------------------------------------------
__global__ __launch_bounds__(256) void context_kernel_bf16(
    const bf16_t* __restrict__ hEncB, const float* __restrict__ attn,
    float* __restrict__ ctx) {
  const int b = blockIdx.x >> 5;
  const int c = blockIdx.x & 31;
  const int t = threadIdx.x;
  __shared__ float w[64];
  if (t < 64) w[t] = attn[b * 2048 + c * 64 + t];
  __syncthreads();
  float a0 = 0.f, a1 = 0.f, a2 = 0.f, a3 = 0.f;
  const bf16_t* base = hEncB + ((size_t)b * 2048 + c * 64) * 1024 + t * 4;
#pragma unroll 4
  for (int s = 0; s < 64; ++s) {
    const bf16x4 h4 = *(const bf16x4*)(base + (size_t)s * 1024);
    const float ws = w[s];
    a0 += ws * (float)h4[0]; a1 += ws * (float)h4[1];
    a2 += ws * (float)h4[2]; a3 += ws * (float)h4[3];
  }
  float* o = ctx + b * 1024 + t * 4;
  atomicAdd(o + 0, a0);
  atomicAdd(o + 1, a1);
  atomicAdd(o + 2, a2);
  atomicAdd(o + 3, a3);
}

__global__ __launch_bounds__(256) void context_kernel_f32(
    const float* __restrict__ hEnc, const float* __restrict__ attn,
    float* __restrict__ ctx) {
  const int b = blockIdx.x >> 5;
  const int c = blockIdx.x & 31;
  const int t = threadIdx.x;
  __shared__ float w[64];
  if (t < 64) w[t] = attn[b * 2048 + c * 64 + t];
  __syncthreads();
  float ax = 0.f, ay = 0.f, az = 0.f, aw = 0.f;
  const float* base = hEnc + ((size_t)b * 2048 + c * 64) * 1024 + t * 4;
#pragma unroll 4
  for (int s = 0; s < 64; ++s) {
    const float4 h4 = *(const float4*)(base + (size_t)s * 1024);
    const float ws = w[s];
    ax += ws * h4.x; ay += ws * h4.y; az += ws * h4.z; aw += ws * h4.w;
  }
  float* o = ctx + b * 1024 + t * 4;
  atomicAdd(o + 0, ax);
  atomicAdd(o + 1, ay);
  atomicAdd(o + 2, az);
  atomicAdd(o + 3, aw);
}

// ---------------------------------------------------------------------------
extern "C" void kernel_launch(void* const* d_in, const int* in_sizes, int n_in,
                              void* d_out, int out_size, void* d_ws, size_t ws_size,
                              hipStream_t stream) {
  const float* hEnc = (const float*)d_in[0];  // (32,2048,1024) fp32
  const float* hDec = (const float*)d_in[1];  // (32,1024) fp32
  const float* W1   = (const float*)d_in[2];  // (2048,1024) fp32
  const float* b1   = (const float*)d_in[3];  // (1024,) fp32
  const float* W2   = (const float*)d_in[4];  // (1024,1) fp32
  const float* b2   = (const float*)d_in[5];  // (1,) fp32
  float* out = (float*)d_out;                 // [0,32768): context; [32768,98304): attn

  // workspace layout: W1T bf16 2MB | dp 128KB | e2 256KB | hEncB bf16 128MB
  char* ws = (char*)d_ws;
  bf16_t* W1T = (bf16_t*)ws;
  float*  dp  = (float*)(ws + 2u * 1024 * 1024);
  float*  e2  = (float*)(ws + 2u * 1024 * 1024 + 128u * 1024);
  bf16_t* hEncB = (bf16_t*)(ws + 2u * 1024 * 1024 + 384u * 1024);
  const size_t need = 2ull * 1024 * 1024 + 384ull * 1024 + 128ull * 1024 * 1024;
  const bool big = ws_size >= need;

  conv_w1t_kernel<<<256, 256, 0, stream>>>(W1, W1T);
  dec_proj_kernel<<<256, 256, 0, stream>>>(hDec, W1, b1, dp, e2);
  if (big) {
    conv_henc_kernel<<<4096, 256, 0, stream>>>(hEnc, hEncB);
    fused_gemm_kernel<true><<<4096, 256, 0, stream>>>(hEnc, hEncB, W1T, dp, W2, e2);
    softmax_kernel<<<32, 256, 0, stream>>>(e2, b2, out + 32768, out);
    context_kernel_bf16<<<1024, 256, 0, stream>>>(hEncB, out + 32768, out);
  } else {
    fused_gemm_kernel<false><<<4096, 256, 0, stream>>>(hEnc, nullptr, W1T, dp, W2, e2);
    softmax_kernel<<<32, 256, 0, stream>>>(e2, b2, out + 32768, out);
    context_kernel_f32<<<1024, 256, 0, stream>>>(hEnc, out + 32768, out);
  }
}

// Round 4
// 621.097 us; speedup vs baseline: 1.2336x; 1.1104x over previous
//
#include <hip/hip_runtime.h>
#include <cstdint>
#include <cstddef>

// Problem constants
#define BB 32
#define SS 2048
#define DD 1024
#define MM (BB * SS)   // 65536 rows of the big GEMM

typedef __bf16 bf16_t;
typedef __bf16 bf16x4 __attribute__((ext_vector_type(4)));
typedef __bf16 bf16x8 __attribute__((ext_vector_type(8)));
typedef float  f32x4  __attribute__((ext_vector_type(4)));

typedef __attribute__((address_space(1))) unsigned int gu32;
typedef __attribute__((address_space(3))) unsigned int lu32;

__device__ __forceinline__ void async_copy16(const void* g, void* l) {
  __builtin_amdgcn_global_load_lds((gu32*)g, (lu32*)l, 16, 0, 0);
}

// ---------------------------------------------------------------------------
// Kernel 1: W1_enc (fp32, [k][n]) -> W1T (bf16, [n][k])  (transpose + convert)
// ---------------------------------------------------------------------------
__global__ __launch_bounds__(256) void conv_w1t_kernel(
    const float* __restrict__ W1, bf16_t* __restrict__ W1T) {
  __shared__ float tile[64][65];
  const int bk = (blockIdx.x & 15) * 64;   // k tile origin
  const int bn = (blockIdx.x >> 4) * 64;   // n tile origin
  const int tx = threadIdx.x & 63;
  const int ty = threadIdx.x >> 6;         // 0..3
#pragma unroll
  for (int i = 0; i < 16; ++i) {
    const int kr = i * 4 + ty;
    tile[kr][tx] = W1[(size_t)(bk + kr) * 1024 + bn + tx];
  }
  __syncthreads();
#pragma unroll
  for (int i = 0; i < 16; ++i) {
    const int nr = i * 4 + ty;
    W1T[(size_t)(bn + nr) * 1024 + bk + tx] = (bf16_t)tile[tx][nr];
  }
}

// ---------------------------------------------------------------------------
// Kernel 2: dec_proj[b][u] = h_dec[b,:] @ W1_dec[:,u] + b1[u]  (fp32)
// Split-K over 2 halves; grid 256 = (b, u-chunk of 128). Also zeroes e2.
// ---------------------------------------------------------------------------
__global__ __launch_bounds__(256) void dec_proj_kernel(
    const float* __restrict__ hDec, const float* __restrict__ W1,
    const float* __restrict__ b1, float* __restrict__ dp,
    float* __restrict__ e2) {
  __shared__ float sred[256];
  const int bidx = blockIdx.x;
  const int b  = bidx >> 3;
  const int uc = bidx & 7;
  const int t  = threadIdx.x;
  e2[bidx * 256 + t] = 0.f;  // 256*256 == 65536
  const int u  = uc * 128 + (t & 127);
  const int kh = t >> 7;
  const float* wd = W1 + (size_t)1024 * 1024 + u;   // W1_dec = rows 1024..2047
  const float* hd = hDec + b * 1024 + kh * 512;
  float acc = 0.f;
#pragma unroll 4
  for (int k = 0; k < 512; ++k)
    acc += hd[k] * wd[(size_t)(kh * 512 + k) * 1024];
  sred[t] = acc;
  __syncthreads();
  if (t < 128) dp[b * 1024 + u] = sred[t] + sred[t + 128] + b1[u];
}

// ---------------------------------------------------------------------------
// Kernel 3: fused bf16 MFMA GEMM + tanh + W2 row-reduction -> e2 partials
//   e2[m] += sum_n tanh(hEnc[m,:]@W1enc[:,n] + dp[b,n]) * W2[n]
// 128x128 tile, 4 waves 2x2, each 64x64 (4x4 frags of 16x16x32), BK=64
// (two 32-k LDS planes per operand -> half the barrier count of BK=32).
// A is read fp32-coalesced (16B/lane, 8 lanes/row) and converted to bf16
// in-register (removes the separate hEnc convert dispatch entirely).
// B staged via global_load_lds (bf16, async).
// grid = 4096 = 512 m-tiles x 8 n-blocks, XCD-swizzled (8 n-blocks of one
// m-tile land on the same XCD -> A slab read from HBM once, served by L2).
// LDS: sA 16KB + sB 16KB, 64B rows, 16B-chunk XOR swizzle (0 conflicts R2/R3).
// ---------------------------------------------------------------------------
__global__ __launch_bounds__(256, 3) void fused_gemm_kernel(
    const float* __restrict__ hEnc, const bf16_t* __restrict__ W1T,
    const float* __restrict__ dp, const float* __restrict__ W2,
    float* __restrict__ e2) {
  __shared__ bf16_t sA[2 * 128 * 32];   // 2 planes x 8KB
  __shared__ bf16_t sB[2 * 128 * 32];

  const int tid  = threadIdx.x;
  const int lane = tid & 63;
  const int wv   = tid >> 6;
  const int wm   = wv >> 1;
  const int wn   = wv & 1;

  const int bid   = blockIdx.x;
  const int mtile = ((bid >> 6) << 3) | (bid & 7);  // [0,512)
  const int nblk  = (bid >> 3) & 7;                 // [0,8)
  const int m0    = mtile * 128;
  const int n0    = nblk * 128;
  const int b     = m0 >> 11;                       // 2048 rows per batch elem

  const int col = lane & 15;
  const int q   = lane >> 4;
  const int sw  = q ^ ((col >> 1) & 3);             // XOR 16B-chunk swizzle

  f32x4 acc[4][4];
#pragma unroll
  for (int mi = 0; mi < 4; ++mi)
#pragma unroll
    for (int ni = 0; ni < 4; ++ni)
      acc[mi][ni] = (f32x4){0.f, 0.f, 0.f, 0.f};

  char* sAc = (char*)sA;
  char* sBc = (char*)sB;

  // B async staging: wave wv fills slabs s0,s1 (16 rows) in each plane.
  // lane -> (row lrow, swizzled 16B k-chunk lc); dest = base + lane*16.
  const int lrow = lane >> 2;
  const int lc   = (lane & 3) ^ ((lane >> 3) & 3);
  const int s0   = wv * 2, s1 = wv * 2 + 1;
  const bf16_t* bG0 = W1T + (size_t)(n0 + s0 * 16 + lrow) * 1024 + lc * 8;
  const bf16_t* bG1 = W1T + (size_t)(n0 + s1 * 16 + lrow) * 1024 + lc * 8;

  // A fp32 staging: thread -> (row frow in 32-row group, 16B chunk fc).
  // Lanes 0..7 cover one 128B row-segment -> fully coalesced.
  const int frow = tid >> 3;          // 0..31
  const int fc   = tid & 7;           // 0..7 (4 floats each)
  const float* aG = hEnc + (size_t)(m0 + frow) * 1024 + fc * 4;
  const unsigned f_off =
      frow * 64u + (unsigned)(((fc >> 1) ^ ((frow >> 1) & 3)) << 4) + (unsigned)(fc & 1) * 8u;

  const unsigned a_rd = (unsigned)((wm * 64 + col) * 64 + sw * 16);
  const unsigned b_rd = (unsigned)((wn * 64 + col) * 64 + sw * 16);

#pragma unroll 1
  for (int k0 = 0; k0 < 1024; k0 += 64) {
    // B: 4 async copies (2 slabs x 2 planes)
    async_copy16(bG0 + k0,      sBc + s0 * 1024);
    async_copy16(bG1 + k0,      sBc + s1 * 1024);
    async_copy16(bG0 + k0 + 32, sBc + 8192 + s0 * 1024);
    async_copy16(bG1 + k0 + 32, sBc + 8192 + s1 * 1024);
    // A: 8 fp32x4 coalesced loads, cvt to bf16, swizzled LDS writes
#pragma unroll
    for (int pl = 0; pl < 2; ++pl)
#pragma unroll
      for (int i = 0; i < 4; ++i) {
        const float4 v = *(const float4*)(aG + k0 + pl * 32 + (size_t)i * 32 * 1024);
        bf16x4 a4;
        a4[0] = (bf16_t)v.x; a4[1] = (bf16_t)v.y;
        a4[2] = (bf16_t)v.z; a4[3] = (bf16_t)v.w;
        *(bf16x4*)(sAc + pl * 8192 + f_off + i * 2048) = a4;
      }
    __syncthreads();
#pragma unroll
    for (int pl = 0; pl < 2; ++pl) {
      bf16x8 af[4], bf[4];
#pragma unroll
      for (int mi = 0; mi < 4; ++mi)
        af[mi] = *(const bf16x8*)(sAc + pl * 8192 + a_rd + mi * 1024);
#pragma unroll
      for (int ni = 0; ni < 4; ++ni)
        bf[ni] = *(const bf16x8*)(sBc + pl * 8192 + b_rd + ni * 1024);
#pragma unroll
      for (int mi = 0; mi < 4; ++mi)
#pragma unroll
        for (int ni = 0; ni < 4; ++ni)
          acc[mi][ni] = __builtin_amdgcn_mfma_f32_16x16x32_bf16(af[mi], bf[ni], acc[mi][ni], 0, 0, 0);
    }
    __syncthreads();
  }

  // Epilogue: rs = sum_n tanh(acc + dp[n]) * W2[n]; butterfly over 16 cols;
  // atomicAdd partials (8 n-blocks x 2 wn-waves accumulate per e2[m]).
  float rs[4][4];
#pragma unroll
  for (int mi = 0; mi < 4; ++mi)
#pragma unroll
    for (int r = 0; r < 4; ++r) rs[mi][r] = 0.f;

  const float* dpb = dp + b * 1024 + n0 + wn * 64 + col;
  const float* w2b = W2 + n0 + wn * 64 + col;
#pragma unroll
  for (int ni = 0; ni < 4; ++ni) {
    const float dpn = dpb[ni * 16];
    const float w2n = w2b[ni * 16];
#pragma unroll
    for (int mi = 0; mi < 4; ++mi)
#pragma unroll
      for (int r = 0; r < 4; ++r) {
        const float x = acc[mi][ni][r] + dpn;
        const float e = __expf(2.f * x);       // tanh(x) = 1 - 2/(e^{2x}+1)
        const float th = 1.f - 2.f / (e + 1.f);
        rs[mi][r] += th * w2n;
      }
  }
#pragma unroll
  for (int off = 1; off < 16; off <<= 1)
#pragma unroll
    for (int mi = 0; mi < 4; ++mi)
#pragma unroll
      for (int r = 0; r < 4; ++r)
        rs[mi][r] += __shfl_xor(rs[mi][r], off, 64);
  if (col == 0) {
#pragma unroll
    for (int mi = 0; mi < 4; ++mi)
#pragma unroll
      for (int r = 0; r < 4; ++r)
        atomicAdd(&e2[m0 + wm * 64 + mi * 16 + q * 4 + r], rs[mi][r]);
  }
}

// ---------------------------------------------------------------------------
// Kernel 4: per-b softmax over S of relu(e2 + b2); writes attn weights,
// zeroes context region (kernel 5 accumulates with atomics).
// ---------------------------------------------------------------------------
__global__ __launch_bounds__(256) void softmax_kernel(
    const float* __restrict__ e2, const float* __restrict__ b2,
    float* __restrict__ attn, float* __restrict__ ctx) {
  const int b = blockIdx.x;
  const int t = threadIdx.x;
  __shared__ float sred[4];
  const float b2v = b2[0];
  float v[8];
  float lmax = 0.f;  // relu output >= 0
#pragma unroll
  for (int i = 0; i < 8; ++i) {
    v[i] = fmaxf(e2[b * 2048 + i * 256 + t] + b2v, 0.f);  // energies2
    lmax = fmaxf(lmax, v[i]);
  }
#pragma unroll
  for (int off = 1; off < 64; off <<= 1) lmax = fmaxf(lmax, __shfl_xor(lmax, off, 64));
  const int wv = t >> 6;
  const int lane = t & 63;
  if (lane == 0) sred[wv] = lmax;
  __syncthreads();
  const float bmax = fmaxf(fmaxf(sred[0], sred[1]), fmaxf(sred[2], sred[3]));
  __syncthreads();
  float ev[8];
  float lsum = 0.f;
#pragma unroll
  for (int i = 0; i < 8; ++i) { ev[i] = __expf(v[i] - bmax); lsum += ev[i]; }
#pragma unroll
  for (int off = 1; off < 64; off <<= 1) lsum += __shfl_xor(lsum, off, 64);
  if (lane == 0) sred[wv] = lsum;
  __syncthreads();
  const float inv = 1.f / (sred[0] + sred[1] + sred[2] + sred[3]);
#pragma unroll
  for (int i = 0; i < 8; ++i) attn[b * 2048 + i * 256 + t] = ev[i] * inv;
#pragma unroll
  for (int i = 0; i < 4; ++i) ctx[b * 1024 + i * 256 + t] = 0.f;
}

// ---------------------------------------------------------------------------
// Kernel 5: context[b,d] = sum_s attn[b,s] * hEnc[b,s,d]
// grid = 32 b x 8 s-chunks(256), 256 threads x float4 covers d=1024.
// 8 atomicAdds per output element.
// ---------------------------------------------------------------------------
__global__ __launch_bounds__(256) void context_kernel(
    const float* __restrict__ hEnc, const float* __restrict__ attn,
    float* __restrict__ ctx) {
  const int b = blockIdx.x >> 3;
  const int c = blockIdx.x & 7;
  const int t = threadIdx.x;
  __shared__ float w[256];
  w[t] = attn[b * 2048 + c * 256 + t];
  __syncthreads();
  float ax = 0.f, ay = 0.f, az = 0.f, aw = 0.f;
  const float* base = hEnc + ((size_t)b * 2048 + c * 256) * 1024 + t * 4;
#pragma unroll 8
  for (int s = 0; s < 256; ++s) {
    const float4 h4 = *(const float4*)(base + (size_t)s * 1024);
    const float ws = w[s];
    ax += ws * h4.x; ay += ws * h4.y; az += ws * h4.z; aw += ws * h4.w;
  }
  float* o = ctx + b * 1024 + t * 4;
  atomicAdd(o + 0, ax);
  atomicAdd(o + 1, ay);
  atomicAdd(o + 2, az);
  atomicAdd(o + 3, aw);
}

// ---------------------------------------------------------------------------
extern "C" void kernel_launch(void* const* d_in, const int* in_sizes, int n_in,
                              void* d_out, int out_size, void* d_ws, size_t ws_size,
                              hipStream_t stream) {
  const float* hEnc = (const float*)d_in[0];  // (32,2048,1024) fp32
  const float* hDec = (const float*)d_in[1];  // (32,1024) fp32
  const float* W1   = (const float*)d_in[2];  // (2048,1024) fp32
  const float* b1   = (const float*)d_in[3];  // (1024,) fp32
  const float* W2   = (const float*)d_in[4];  // (1024,1) fp32
  const float* b2   = (const float*)d_in[5];  // (1,) fp32
  float* out = (float*)d_out;                 // [0,32768): context; [32768,98304): attn

  // workspace: W1T bf16 2MB | dp fp32 128KB | e2 fp32 256KB  (2.375 MB)
  char* ws = (char*)d_ws;
  bf16_t* W1T = (bf16_t*)ws;
  float*  dp  = (float*)(ws + 2u * 1024 * 1024);
  float*  e2  = (float*)(ws + 2u * 1024 * 1024 + 128u * 1024);

  conv_w1t_kernel<<<256, 256, 0, stream>>>(W1, W1T);
  dec_proj_kernel<<<256, 256, 0, stream>>>(hDec, W1, b1, dp, e2);
  fused_gemm_kernel<<<4096, 256, 0, stream>>>(hEnc, W1T, dp, W2, e2);
  softmax_kernel<<<32, 256, 0, stream>>>(e2, b2, out + 32768, out);
  context_kernel<<<256, 256, 0, stream>>>(hEnc, out + 32768, out);
}